// Round 10
// baseline (762.107 us; speedup 1.0000x reference)
//
#include <hip/hip_runtime.h>
#include <hip/hip_bf16.h>

// B=64, D=1024, M=1024, DMODEL=1024, PRED_LEN=96
//   hp[b,i,f] = sum_c h[b,i,c]*pw[f,c] + pb[f]
//   P [b,i,f] = sum_m u[i,m]*lam[b,f,m]
//   diag[b,i] = sum_f hp[b,i,f]*P[b,i,f];  out[b,i,:] = diag[b,i] + bias[i]
//
// 256^2-tile 8-wave GEMMs. Big f32 operand (h / lam) is reg-staged
// (global->reg->cvt->swizzled ds_write, T14 issue-early/write-late); small
// bf16 operand (pw / u, pre-converted 2MB) via global_load_lds. Counted
// vmcnt ledger keeps 1 tile in flight. K1 writes hp (bf16) to ws; K2 fuses
// the hadamard/rowsum diag epilogue. LDS 128KB dbuf, 1 block/CU.

#define D_    1024
#define BATCH 64
#define PRED  96

typedef __attribute__((ext_vector_type(8))) short  bf16x8;
typedef __attribute__((ext_vector_type(8))) ushort ushort8;
typedef __attribute__((ext_vector_type(4))) float  f32x4;
typedef __attribute__((ext_vector_type(4))) ushort us4;

__device__ __forceinline__ ushort f2bf(float f){
  union { __hip_bfloat16 b; ushort u; } cv;
  cv.b = __float2bfloat16(f);
  return cv.u;
}
__device__ __forceinline__ float bf2f(ushort v){
  union { ushort u; __hip_bfloat16 b; } cv;
  cv.u = v;
  return __bfloat162float(cv.b);
}

// bijective XCD swizzle (m204 form)
__device__ __forceinline__ int xcd_swz(int orig, int nwg){
  int q = nwg >> 3, r = nwg & 7;
  int x = orig & 7, o = orig >> 3;
  return (x < r ? x*(q+1) : r*(q+1) + (x-r)*q) + o;
}

// async global->LDS, 16B/lane; LDS dest = wave-uniform base + lane*16
__device__ __forceinline__ void gload16(const ushort* g, ushort* l){
  __builtin_amdgcn_global_load_lds(
      (const __attribute__((address_space(1))) void*)g,
      (__attribute__((address_space(3))) void*)l, 16, 0, 0);
}

// ------- f32 -> bf16 convert (tiny u/pw only) -------
__global__ __launch_bounds__(256) void cvt_bf16(const float* __restrict__ in,
                                                ushort* __restrict__ out, int n4){
  int stride = (int)gridDim.x * 256;
  for (int i = (int)blockIdx.x*256 + (int)threadIdx.x; i < n4; i += stride){
    f32x4 a = *((const f32x4*)in + i);
    us4 o;
    o.x = f2bf(a.x); o.y = f2bf(a.y); o.z = f2bf(a.z); o.w = f2bf(a.w);
    *(us4*)(out + (size_t)i*4) = o;
  }
}

// frag read from a 256x64 bf16 tile, 16B-chunk XOR swizzle (proven layout)
__device__ __forceinline__ bf16x8 fragr(const ushort* s, int r, int cb){
  return *(const bf16x8*)(s + r*64 + ((cb ^ (r & 7)) << 3));
}

// ---- 256x256x1024 contraction core.  F32A=1: f32 side is the A (row/i)
// operand; F32A=0: f32 side is the B (row/f) operand.  acc[8][4] per wave
// (wave = 128 rows x 64 cols of the 256x256 tile; 8 waves as 2x4).
template<int F32A>
__device__ __forceinline__ void core256(
    const float* __restrict__ PF, const ushort* __restrict__ PB,
    ushort* sA0, ushort* sA1, ushort* sB0, ushort* sB1,
    f32x4 (&acc)[8][4], int lane, int wv, int wr, int wc)
{
  int tid  = wv*64 + lane;
  int row  = tid >> 1;                        // f32-side staging row (0..255)
  int half = tid & 1;                         // 32-f32 half of the 64-col row
  int r7   = row & 7;
  int srow = lane >> 3;                       // bf16-side gload row-in-8
  int scol = (((lane & 7) ^ srow) << 3);      // pre-swizzled source chunk

  ushort* sF0 = F32A ? sA0 : sB0;  ushort* sF1 = F32A ? sA1 : sB1;
  ushort* sG0 = F32A ? sB0 : sA0;  ushort* sG1 = F32A ? sB1 : sA1;

  f32x4 rS[8];

#define ISSF(TOFF)                                                            \
  { const float* _p = PF + (TOFF) + (size_t)row*D_ + half*32;                 \
    _Pragma("unroll")                                                         \
    for (int j = 0; j < 8; ++j) rS[j] = ((const f32x4*)_p)[j]; }

#define ISSB(TOFF, SGT)                                                       \
  { _Pragma("unroll")                                                         \
    for (int q = 0; q < 4; ++q){                                              \
      int _r0 = q*64 + wv*8;                                                  \
      gload16(PB + (TOFF) + (size_t)(_r0 + srow)*D_ + scol, (SGT) + _r0*64); } }

#define DSWR(SFT)                                                             \
  { _Pragma("unroll")                                                         \
    for (int jj = 0; jj < 4; ++jj){                                           \
      ushort8 _w;                                                             \
      _w[0]=f2bf(rS[2*jj][0]);   _w[1]=f2bf(rS[2*jj][1]);                     \
      _w[2]=f2bf(rS[2*jj][2]);   _w[3]=f2bf(rS[2*jj][3]);                     \
      _w[4]=f2bf(rS[2*jj+1][0]); _w[5]=f2bf(rS[2*jj+1][1]);                   \
      _w[6]=f2bf(rS[2*jj+1][2]); _w[7]=f2bf(rS[2*jj+1][3]);                   \
      *(ushort8*)((SFT) + row*64 + ((((half<<2)+jj) ^ r7) << 3)) = _w; } }

  __builtin_amdgcn_s_barrier();       // LDS handoff guard (prev reads done)

  // ---- prologue: tiles 0 and 1 ----
  ISSF(0); ISSB(0, sG0);
  asm volatile("s_waitcnt vmcnt(4)" ::: "memory");   // A0 regs landed
  DSWR(sF0);
  ISSF(64); ISSB(64, sG1);
  asm volatile("s_waitcnt lgkmcnt(0)" ::: "memory");
  asm volatile("s_waitcnt vmcnt(12)" ::: "memory");  // B0 in LDS
  __builtin_amdgcn_s_barrier();

  // ledger invariant at tile t entry: outstanding = [A(t+1):8, B(t+1):4]
  for (int t = 0; t < 16; ++t){
    ushort* sAc = (t & 1) ? sA1 : sA0;
    ushort* sBc = (t & 1) ? sB1 : sB0;
    ushort* sFn = (t & 1) ? sF0 : sF1;     // f32 dest for tile t+1
    ushort* sGc = (t & 1) ? sG1 : sG0;     // gload dest for tile t+2 (parity t)

    #pragma unroll
    for (int kk = 0; kk < 2; ++kk){
      bf16x8 af[8], bfr[4];
      int cb = kk*4 + (lane >> 4);
      #pragma unroll
      for (int x = 0; x < 8; ++x)
        af[x]  = fragr(sAc, wr*128 + x*16 + (lane & 15), cb);
      #pragma unroll
      for (int y = 0; y < 4; ++y)
        bfr[y] = fragr(sBc, wc*64 + y*16 + (lane & 15), cb);
      asm volatile("s_waitcnt lgkmcnt(0)" ::: "memory");
      __builtin_amdgcn_sched_barrier(0);
      __builtin_amdgcn_s_setprio(1);
      #pragma unroll
      for (int x = 0; x < 8; ++x)
        #pragma unroll
        for (int y = 0; y < 4; ++y)
          acc[x][y] = __builtin_amdgcn_mfma_f32_16x16x32_bf16(
                          af[x], bfr[y], acc[x][y], 0, 0, 0);
      __builtin_amdgcn_s_setprio(0);
    }
    __builtin_amdgcn_s_barrier();          // all waves done reading buf cur

    if (t < 15){
      asm volatile("s_waitcnt vmcnt(4)" ::: "memory");   // A(t+1) regs landed
      DSWR(sFn);
    }
    if (t < 14){ ISSF((t+2)*64); ISSB((t+2)*64, sGc); }
    if (t < 15){
      asm volatile("s_waitcnt lgkmcnt(0)" ::: "memory"); // A(t+1) writes done
      if (t < 14) asm volatile("s_waitcnt vmcnt(12)" ::: "memory"); // B(t+1)
      else        asm volatile("s_waitcnt vmcnt(0)"  ::: "memory");
      __builtin_amdgcn_s_barrier();        // buf nxt fully staged
    }
  }
#undef ISSF
#undef ISSB
#undef DSWR
}

// ---------------- K1: hp = bf16( h @ pw^T + pb ) ----------------
__global__ __launch_bounds__(512, 2) void k1_hp(
    const float* __restrict__ h, const ushort* __restrict__ pwbf,
    const float* __restrict__ pb, ushort* __restrict__ hp)
{
  __shared__ ushort sA0[256*64], sA1[256*64], sB0[256*64], sB1[256*64];
  int bid = xcd_swz((int)blockIdx.x, (int)gridDim.x);
  int bl = bid >> 4;
  int t_ = bid & 15;
  int iblk = t_ >> 2, fblk = t_ & 3;
  const float*  PF = h    + ((size_t)bl << 20) + (size_t)(iblk*256) * D_;
  const ushort* PB = pwbf + (size_t)(fblk*256) * D_;
  int tid = threadIdx.x, lane = tid & 63, wv = tid >> 6;
  int wr = wv >> 2, wc = wv & 3;

  f32x4 acc[8][4];
  #pragma unroll
  for (int x = 0; x < 8; ++x)
    #pragma unroll
    for (int y = 0; y < 4; ++y) acc[x][y] = (f32x4){0.f,0.f,0.f,0.f};

  core256<1>(PF, PB, sA0, sA1, sB0, sB1, acc, lane, wv, wr, wc);

  // epilogue: +pb, store bf16.  C/D map: col=lane&15, row=(lane>>4)*4+r
  ushort* hpb = hp + ((size_t)bl << 20);
  #pragma unroll
  for (int y = 0; y < 4; ++y){
    int gf = fblk*256 + wc*64 + y*16 + (lane & 15);
    float pbv = pb[gf];
    #pragma unroll
    for (int x = 0; x < 8; ++x){
      int gi0 = iblk*256 + wr*128 + x*16 + (lane >> 4)*4;
      #pragma unroll
      for (int r = 0; r < 4; ++r)
        hpb[(size_t)(gi0 + r)*D_ + gf] = f2bf(acc[x][y][r] + pbv);
    }
  }
}

// -------- K2: P = u @ lam^T ; fused diag partial = rowsum(P .* hp) --------
__global__ __launch_bounds__(512, 2) void k2_diag(
    const ushort* __restrict__ ubf, const float* __restrict__ lam,
    const ushort* __restrict__ hp, float* __restrict__ partial, int b0)
{
  __shared__ ushort sA0[256*64], sA1[256*64], sB0[256*64], sB1[256*64];
  int bid = xcd_swz((int)blockIdx.x, (int)gridDim.x);
  int bl = bid >> 4;
  int t_ = bid & 15;
  int iblk = t_ >> 2, fblk = t_ & 3;
  const ushort* PB = ubf + (size_t)(iblk*256) * D_;
  const float*  PF = lam + ((size_t)bl << 20) + (size_t)(fblk*256) * D_;
  int tid = threadIdx.x, lane = tid & 63, wv = tid >> 6;
  int wr = wv >> 2, wc = wv & 3;

  f32x4 acc[8][4];
  #pragma unroll
  for (int x = 0; x < 8; ++x)
    #pragma unroll
    for (int y = 0; y < 4; ++y) acc[x][y] = (f32x4){0.f,0.f,0.f,0.f};

  core256<0>(PF, PB, sA0, sA1, sB0, sB1, acc, lane, wv, wr, wc);

  // epilogue: ps[x][r] = sum over this wave's 64 cols of P .* hp
  const ushort* hpb = hp + ((size_t)bl << 20);
  f32x4 ps[8];
  #pragma unroll
  for (int x = 0; x < 8; ++x) ps[x] = (f32x4){0.f,0.f,0.f,0.f};
  #pragma unroll
  for (int y = 0; y < 4; ++y){
    int gf = fblk*256 + wc*64 + y*16 + (lane & 15);
    #pragma unroll
    for (int x = 0; x < 8; ++x){
      int gi0 = iblk*256 + wr*128 + x*16 + (lane >> 4)*4;
      #pragma unroll
      for (int r = 0; r < 4; ++r)
        ps[x][r] += acc[x][y][r] * bf2f(hpb[(size_t)(gi0 + r)*D_ + gf]);
    }
  }
  // butterfly over the 16 cols (lane bits 0..3); preserves row group (lane>>4)
  #pragma unroll
  for (int x = 0; x < 8; ++x)
    #pragma unroll
    for (int r = 0; r < 4; ++r){
      float v = ps[x][r];
      #pragma unroll
      for (int mm = 1; mm < 16; mm <<= 1) v += __shfl_xor(v, mm, 64);
      ps[x][r] = v;
    }
  // deterministic partial strips: strip = fblk*4 + wc  (16 strips)
  if ((lane & 15) == 0){
    int strip = fblk*4 + wc;
    float* pdst = partial + (size_t)strip*(BATCH*D_) + (size_t)(b0 + bl)*D_;
    #pragma unroll
    for (int x = 0; x < 8; ++x){
      int gi0 = iblk*256 + wr*128 + x*16 + (lane >> 4)*4;
      #pragma unroll
      for (int r = 0; r < 4; ++r) pdst[gi0 + r] = ps[x][r];
    }
  }
}

// ---------------- K3: diag = sum(strips) + bias; broadcast to 96 ----------------
__global__ __launch_bounds__(128) void bcast_out(
    const float* __restrict__ partial, const float* __restrict__ bias,
    float* __restrict__ out)
{
  int row = blockIdx.x;             // b*1024 + i
  int i = row & (D_-1);
  float s = bias[i];
  #pragma unroll
  for (int st = 0; st < 16; ++st) s += partial[(size_t)st*(BATCH*D_) + row];
  if (threadIdx.x < PRED) out[(size_t)row*PRED + threadIdx.x] = s;
}

// ---------------- emergency path: no workspace needed (slow, correct) ----------------
__global__ __launch_bounds__(256) void emergency_fused(
    const float* __restrict__ h, const float* __restrict__ lam,
    const float* __restrict__ uu, const float* __restrict__ bias,
    const float* __restrict__ pw, const float* __restrict__ pb,
    float* __restrict__ out)
{
  int b = blockIdx.x >> 10;
  int i = blockIdx.x & (D_-1);
  __shared__ float hps[D_];
  __shared__ float red[4];
  __shared__ float dv;
  const float* hrow = h + ((size_t)b << 20) + (size_t)i*D_;
  for (int f = threadIdx.x; f < D_; f += 256){
    const float* pwr = pw + (size_t)f*D_;
    float s = pb[f];
    for (int c = 0; c < D_; ++c) s += hrow[c]*pwr[c];
    hps[f] = s;
  }
  __syncthreads();
  const float* urow = uu + (size_t)i*D_;
  float d = 0.f;
  for (int f = threadIdx.x; f < D_; f += 256){
    const float* lr = lam + ((size_t)b << 20) + (size_t)f*D_;
    float p = 0.f;
    for (int m = 0; m < D_; ++m) p += lr[m]*urow[m];
    d += hps[f]*p;
  }
  for (int off = 32; off; off >>= 1) d += __shfl_down(d, off, 64);
  if ((threadIdx.x & 63) == 0) red[threadIdx.x >> 6] = d;
  __syncthreads();
  if (threadIdx.x == 0) dv = red[0]+red[1]+red[2]+red[3] + bias[i];
  __syncthreads();
  if (threadIdx.x < PRED) out[(size_t)blockIdx.x*PRED + threadIdx.x] = dv;
}

extern "C" void kernel_launch(void* const* d_in, const int* in_sizes, int n_in,
                              void* d_out, int out_size, void* d_ws, size_t ws_size,
                              hipStream_t stream) {
  const float* h    = (const float*)d_in[0];
  const float* lam  = (const float*)d_in[1];
  const float* uu   = (const float*)d_in[2];
  const float* bias = (const float*)d_in[3];
  const float* pw   = (const float*)d_in[4];
  const float* pb   = (const float*)d_in[5];
  float* out = (float*)d_out;

  const size_t MB = 1ull << 20;
  const size_t FIXED = 4*MB /*partial*/ + 2*MB /*u_bf*/ + 2*MB /*pw_bf*/;

  if (ws_size >= FIXED + 2*MB) {
    float*  partial = (float*)d_ws;
    ushort* u_bf    = (ushort*)((char*)d_ws + 4*MB);
    ushort* pw_bf   = (ushort*)((char*)d_ws + 6*MB);
    ushort* hp      = (ushort*)((char*)d_ws + 8*MB);
    int cnb = (int)((ws_size - FIXED) / (2*MB));    // hp: 2MB per batch
    if (cnb > BATCH) cnb = BATCH;

    cvt_bf16<<<dim3(512), dim3(256), 0, stream>>>(uu, u_bf, 262144);
    cvt_bf16<<<dim3(512), dim3(256), 0, stream>>>(pw, pw_bf, 262144);

    for (int b0 = 0; b0 < BATCH; b0 += cnb){
      int nb = (BATCH - b0) < cnb ? (BATCH - b0) : cnb;
      k1_hp  <<<dim3(nb*16), dim3(512), 0, stream>>>(h + ((size_t)b0 << 20), pw_bf, pb, hp);
      k2_diag<<<dim3(nb*16), dim3(512), 0, stream>>>(u_bf, lam + ((size_t)b0 << 20), hp, partial, b0);
    }
    bcast_out<<<dim3(BATCH*D_), dim3(128), 0, stream>>>(partial, bias, out);
  } else {
    emergency_fused<<<dim3(BATCH*D_), dim3(256), 0, stream>>>(h, lam, uu, bias, pw, pb, out);
  }
}

// Round 11
// 744.826 us; speedup vs baseline: 1.0232x; 1.0232x over previous
//
#include <hip/hip_runtime.h>
#include <hip/hip_bf16.h>

// B=64, D=1024, M=1024, DMODEL=1024, PRED_LEN=96
//   hp[b,i,f] = sum_c h[b,i,c]*pw[f,c] + pb[f]
//   P [b,i,f] = sum_m u[i,m]*lam[b,f,m]
//   diag[b,i] = sum_f hp[b,i,f]*P[b,i,f];  out[b,i,:] = diag[b,i] + bias[i]
//
// ONE fused kernel (R5's proven 128^2 2-barrier skeleton, 2 blocks/CU).
// Big f32 operand (h loop1 / lam loop2) is reg-staged: 8x global dwordx4 ->
// regs (double-buffered, ~2 phases of latency cover) -> f2bf -> swizzled
// ds_write_b128 placed AFTER the MFMA cluster. bf16 in LDS => frag path and
// LDS byte budget identical to R5 (0 conflicts). Small operand (pw/u, 2MB
// pre-cvt) via global_load_lds as before. No big cvt kernels, no hp traffic.

#define D_    1024
#define BATCH 64
#define PRED  96

typedef __attribute__((ext_vector_type(8))) short  bf16x8;
typedef __attribute__((ext_vector_type(8))) ushort ushort8;
typedef __attribute__((ext_vector_type(4))) float  f32x4;
typedef __attribute__((ext_vector_type(4))) ushort us4;

__device__ __forceinline__ ushort f2bf(float f){
  union { __hip_bfloat16 b; ushort u; } cv;
  cv.b = __float2bfloat16(f);
  return cv.u;
}
__device__ __forceinline__ float bf2f(ushort v){
  union { ushort u; __hip_bfloat16 b; } cv;
  cv.u = v;
  return __bfloat162float(cv.b);
}

// bijective XCD swizzle (m204 form)
__device__ __forceinline__ int xcd_swz(int orig, int nwg){
  int q = nwg >> 3, r = nwg & 7;
  int x = orig & 7, o = orig >> 3;
  return (x < r ? x*(q+1) : r*(q+1) + (x-r)*q) + o;
}

// async global->LDS, 16B/lane; LDS dest = wave-uniform base + lane*16
__device__ __forceinline__ void gload16(const ushort* g, ushort* l){
  __builtin_amdgcn_global_load_lds(
      (const __attribute__((address_space(1))) void*)g,
      (__attribute__((address_space(3))) void*)l, 16, 0, 0);
}

// ------- f32 -> bf16 convert (tiny u/pw only) -------
__global__ __launch_bounds__(256) void cvt_bf16(const float* __restrict__ in,
                                                ushort* __restrict__ out, int n4){
  int stride = (int)gridDim.x * 256;
  for (int i = (int)blockIdx.x*256 + (int)threadIdx.x; i < n4; i += stride){
    f32x4 a = *((const f32x4*)in + i);
    us4 o;
    o.x = f2bf(a.x); o.y = f2bf(a.y); o.z = f2bf(a.z); o.w = f2bf(a.w);
    *(us4*)(out + (size_t)i*4) = o;
  }
}

// frag read from 128x64 bf16 tile, 16B-chunk XOR swizzle (proven, 0 conflicts)
__device__ __forceinline__ bf16x8 fragr(const ushort* s, int r, int cb){
  return *(const bf16x8*)(s + r*64 + ((cb ^ (r & 7)) << 3));
}

// ---- 128x128x1024 contraction, R5 skeleton + reg-staged f32 side.
// F32A=1: f32 side is the A (i-rows) operand; F32A=0: it's B (f-rows).
template<int F32A>
__device__ __forceinline__ void core_mix(
    const float* __restrict__ pf,      // per-thread f32 src base (row,half applied)
    const ushort* __restrict__ PB,     // bf16 panel base
    ushort* sF0_, ushort* sF1_, ushort* sG0_, ushort* sG1_,
    f32x4 (&acc)[4][4],
    int lane, int wv, int wr, int wc, int srow, int scol, const int (&dswo)[4])
{
  f32x4 rSa[8], rSb[8];

#define ISSF(TILE, RS)                                                        \
  { const float* _p = pf + (TILE)*64;                                         \
    _Pragma("unroll")                                                         \
    for (int j = 0; j < 8; ++j) RS[j] = ((const f32x4*)_p)[j]; }

#define ISSB(TILE, SGT)                                                       \
  { _Pragma("unroll")                                                         \
    for (int q = 0; q < 4; ++q){                                              \
      int _r0 = q*32 + wv*8;                                                  \
      gload16(PB + (size_t)(TILE)*64 + (size_t)(_r0 + srow)*D_ + scol,        \
              (SGT) + _r0*64); } }

#define DSW(RS, SDST)                                                         \
  { _Pragma("unroll")                                                         \
    for (int jj = 0; jj < 4; ++jj){                                           \
      ushort8 _w;                                                             \
      _w[0]=f2bf(RS[2*jj][0]);   _w[1]=f2bf(RS[2*jj][1]);                     \
      _w[2]=f2bf(RS[2*jj][2]);   _w[3]=f2bf(RS[2*jj][3]);                     \
      _w[4]=f2bf(RS[2*jj+1][0]); _w[5]=f2bf(RS[2*jj+1][1]);                   \
      _w[6]=f2bf(RS[2*jj+1][2]); _w[7]=f2bf(RS[2*jj+1][3]);                   \
      *(ushort8*)((SDST) + dswo[jj]) = _w; } }

// Phase T (parity CUR): ISSF(T+3) early; entry barrier; frag reads tile T;
// lgkm+schedbar+barrier; ISSB(T+2) into freed sG; MFMA; counted vmcnt;
// DSW(tile T+2) into freed sF (after MFMA — off the critical path).
// Cross-wave DSW visibility: next phase's lgkmcnt(0)+barrier drains it
// before anyone reads that buffer (read happens 2 phases later).
#define PHASE(T, CUR, RS_DSW, RS_ISSF)                                        \
  {                                                                           \
    if ((T) <= 12) ISSF((T)+3, RS_ISSF);                                      \
    __builtin_amdgcn_s_barrier();                                             \
    ushort* sFc = (CUR) ? sF1_ : sF0_;                                        \
    ushort* sGc = (CUR) ? sG1_ : sG0_;                                        \
    const ushort* sAc = F32A ? sFc : sGc;                                     \
    const ushort* sBc = F32A ? sGc : sFc;                                     \
    bf16x8 af[2][4], bfr[2][4];                                               \
    _Pragma("unroll")                                                         \
    for (int kk = 0; kk < 2; ++kk){                                           \
      int cb = kk*4 + (lane >> 4);                                            \
      _Pragma("unroll")                                                       \
      for (int x = 0; x < 4; ++x){                                            \
        af[kk][x]  = fragr(sAc, wr*64 + x*16 + (lane & 15), cb);              \
        bfr[kk][x] = fragr(sBc, wc*64 + x*16 + (lane & 15), cb);              \
      }                                                                       \
    }                                                                         \
    asm volatile("s_waitcnt lgkmcnt(0)" ::: "memory");                        \
    __builtin_amdgcn_sched_barrier(0);                                        \
    __builtin_amdgcn_s_barrier();                                             \
    if ((T) <= 13) ISSB((T)+2, sGc);                                          \
    __builtin_amdgcn_s_setprio(1);                                            \
    _Pragma("unroll")                                                         \
    for (int kk = 0; kk < 2; ++kk)                                            \
      _Pragma("unroll")                                                       \
      for (int x = 0; x < 4; ++x)                                             \
        _Pragma("unroll")                                                     \
        for (int y = 0; y < 4; ++y)                                           \
          acc[x][y] = __builtin_amdgcn_mfma_f32_16x16x32_bf16(                \
                          af[kk][x], bfr[kk][y], acc[x][y], 0, 0, 0);         \
    __builtin_amdgcn_s_setprio(0);                                            \
    if ((T) <= 12)      asm volatile("s_waitcnt vmcnt(12)" ::: "memory");     \
    else if ((T) == 13) asm volatile("s_waitcnt vmcnt(4)"  ::: "memory");     \
    else if ((T) == 14) asm volatile("s_waitcnt vmcnt(0)"  ::: "memory");     \
    if ((T) <= 13) DSW(RS_DSW, sFc);                                          \
  }

  // prologue: tiles 0,1 staged; F(2) in regs.  FIFO: F0,B0,F1,B1 -> +F2.
  ISSF(0, rSa); ISSB(0, sG0_);
  ISSF(1, rSb); ISSB(1, sG1_);
  asm volatile("s_waitcnt vmcnt(16)" ::: "memory");   // F0 landed
  DSW(rSa, sF0_);
  ISSF(2, rSa);
  asm volatile("s_waitcnt vmcnt(12)" ::: "memory");   // B0, F1 landed
  DSW(rSb, sF1_);
  asm volatile("s_waitcnt lgkmcnt(0)" ::: "memory");
  __builtin_amdgcn_s_barrier();

  for (int tt = 0; tt < 8; ++tt){
    PHASE(2*tt,   0, rSa, rSb)
    PHASE(2*tt+1, 1, rSb, rSa)
  }
#undef ISSF
#undef ISSB
#undef DSW
#undef PHASE
}

// ---------------- fused: hp-tile GEMM + P-tile GEMM + diag epilogue ----------------
__global__ __launch_bounds__(256, 2) void fused_diag(
    const float* __restrict__ h, const ushort* __restrict__ pwbf,
    const ushort* __restrict__ ubf, const float* __restrict__ lam,
    const float* __restrict__ pb, float* __restrict__ partial)
{
  __shared__ ushort sA0[128*64], sA1[128*64], sB0[128*64], sB1[128*64]; // 64 KB
  int bid = xcd_swz((int)blockIdx.x, (int)gridDim.x);
  int bl = bid >> 6;                 // batch
  int t_ = bid & 63;
  int it = t_ >> 3, ft = t_ & 7;
  int tid = threadIdx.x, lane = tid & 63, wv = tid >> 6;
  int wr = wv >> 1, wc = wv & 1;
  // bf16-side gload map (16B = 8-bf16 chunks, pre-swizzled source)
  int srow = lane >> 3;
  int scol = (((lane & 7) ^ srow) << 3);
  // f32-side reg-stage map: thread -> (row = tid>>1, half = tid&1), 32 floats
  int rrow = tid >> 1, rhalf = tid & 1;
  int dswo[4];
  #pragma unroll
  for (int jj = 0; jj < 4; ++jj)
    dswo[jj] = rrow*64 + (((rhalf*4 + jj) ^ (rrow & 7)) << 3);

  f32x4 acc[4][4];
  #pragma unroll
  for (int x = 0; x < 4; ++x)
    #pragma unroll
    for (int y = 0; y < 4; ++y) acc[x][y] = (f32x4){0.f,0.f,0.f,0.f};

  // ---- loop 1: hp-tile = h @ pw^T  (h f32 reg-staged -> A; pw gload -> B) ----
  const float*  pfH = h + ((size_t)bl << 20) + (size_t)(it*128 + rrow)*D_ + rhalf*32;
  const ushort* PBW = pwbf + (size_t)(ft*128) * D_;
  core_mix<1>(pfH, PBW, sA0, sA1, sB0, sB1, acc, lane, wv, wr, wc, srow, scol, dswo);

  // pack hp (+pb) to bf16 in registers; reset acc for loop 2
  us4 hp_pk[4][4];
  #pragma unroll
  for (int y = 0; y < 4; ++y){
    int gk = ft*128 + wc*64 + y*16 + (lane & 15);
    float pbv = pb[gk];
    #pragma unroll
    for (int x = 0; x < 4; ++x){
      us4 p;
      p.x = f2bf(acc[x][y][0] + pbv); p.y = f2bf(acc[x][y][1] + pbv);
      p.z = f2bf(acc[x][y][2] + pbv); p.w = f2bf(acc[x][y][3] + pbv);
      hp_pk[x][y] = p;
      acc[x][y] = (f32x4){0.f,0.f,0.f,0.f};
    }
  }

  // ---- loop 2: P-tile = u @ lam^T  (lam f32 reg-staged -> B; u gload -> A) ----
  const float*  pfL = lam + ((size_t)bl << 20) + (size_t)(ft*128 + rrow)*D_ + rhalf*32;
  const ushort* PBU = ubf + (size_t)(it*128) * D_;
  core_mix<0>(pfL, PBU, sB0, sB1, sA0, sA1, acc, lane, wv, wr, wc, srow, scol, dswo);

  // ---- epilogue: ps = rowsum over this wave's 64 cols of hp .* P ----
  f32x4 ps[4];
  #pragma unroll
  for (int x = 0; x < 4; ++x) ps[x] = (f32x4){0.f,0.f,0.f,0.f};
  #pragma unroll
  for (int y = 0; y < 4; ++y)
    #pragma unroll
    for (int x = 0; x < 4; ++x){
      ps[x][0] += bf2f(hp_pk[x][y].x) * acc[x][y][0];
      ps[x][1] += bf2f(hp_pk[x][y].y) * acc[x][y][1];
      ps[x][2] += bf2f(hp_pk[x][y].z) * acc[x][y][2];
      ps[x][3] += bf2f(hp_pk[x][y].w) * acc[x][y][3];
    }
  // butterfly over the 16 cols (lane bits 0..3); preserves row group (lane>>4)
  #pragma unroll
  for (int x = 0; x < 4; ++x)
    #pragma unroll
    for (int r = 0; r < 4; ++r){
      float v = ps[x][r];
      #pragma unroll
      for (int mm = 1; mm < 16; mm <<= 1) v += __shfl_xor(v, mm, 64);
      ps[x][r] = v;
    }
  // deterministic partial strips: strip = ft*2 + wc  (16 strips)
  if ((lane & 15) == 0){
    int strip = ft*2 + wc;
    float* pdst = partial + (size_t)strip*(BATCH*D_) + (size_t)bl*D_;
    #pragma unroll
    for (int x = 0; x < 4; ++x){
      int gi0 = it*128 + wr*64 + x*16 + (lane >> 4)*4;
      #pragma unroll
      for (int r = 0; r < 4; ++r) pdst[gi0 + r] = ps[x][r];
    }
  }
}

// ------- K3: diag = sum(strips) + bias; broadcast to 96 (512-block grid) -------
__global__ __launch_bounds__(256) void bcast_out(
    const float* __restrict__ partial, const float* __restrict__ bias,
    float* __restrict__ out)
{
  int tid = threadIdx.x;
  int row = (int)blockIdx.x*128 + (tid >> 1);   // 512 blocks x 128 rows
  int half = tid & 1;
  int i = row & (D_-1);
  float s = bias[i];
  #pragma unroll
  for (int st = 0; st < 16; ++st) s += partial[(size_t)st*(BATCH*D_) + row];
  f32x4 v = {s, s, s, s};
  float* dst = out + (size_t)row*PRED + half*48;
  #pragma unroll
  for (int j = 0; j < 12; ++j) ((f32x4*)dst)[j] = v;
}

// ---------------- emergency path: no workspace needed (slow, correct) ----------------
__global__ __launch_bounds__(256) void emergency_fused(
    const float* __restrict__ h, const float* __restrict__ lam,
    const float* __restrict__ uu, const float* __restrict__ bias,
    const float* __restrict__ pw, const float* __restrict__ pb,
    float* __restrict__ out)
{
  int b = blockIdx.x >> 10;
  int i = blockIdx.x & (D_-1);
  __shared__ float hps[D_];
  __shared__ float red[4];
  __shared__ float dv;
  const float* hrow = h + ((size_t)b << 20) + (size_t)i*D_;
  for (int f = threadIdx.x; f < D_; f += 256){
    const float* pwr = pw + (size_t)f*D_;
    float s = pb[f];
    for (int c = 0; c < D_; ++c) s += hrow[c]*pwr[c];
    hps[f] = s;
  }
  __syncthreads();
  const float* urow = uu + (size_t)i*D_;
  float d = 0.f;
  for (int f = threadIdx.x; f < D_; f += 256){
    const float* lr = lam + ((size_t)b << 20) + (size_t)f*D_;
    float p = 0.f;
    for (int m = 0; m < D_; ++m) p += lr[m]*urow[m];
    d += hps[f]*p;
  }
  for (int off = 32; off; off >>= 1) d += __shfl_down(d, off, 64);
  if ((threadIdx.x & 63) == 0) red[threadIdx.x >> 6] = d;
  __syncthreads();
  if (threadIdx.x == 0) dv = red[0]+red[1]+red[2]+red[3] + bias[i];
  __syncthreads();
  if (threadIdx.x < PRED) out[(size_t)blockIdx.x*PRED + threadIdx.x] = dv;
}

extern "C" void kernel_launch(void* const* d_in, const int* in_sizes, int n_in,
                              void* d_out, int out_size, void* d_ws, size_t ws_size,
                              hipStream_t stream) {
  const float* h    = (const float*)d_in[0];
  const float* lam  = (const float*)d_in[1];
  const float* uu   = (const float*)d_in[2];
  const float* bias = (const float*)d_in[3];
  const float* pw   = (const float*)d_in[4];
  const float* pb   = (const float*)d_in[5];
  float* out = (float*)d_out;

  const size_t MB = 1ull << 20;

  if (ws_size >= 8*MB) {
    float*  partial = (float*)d_ws;                       // 4 MB
    ushort* u_bf    = (ushort*)((char*)d_ws + 4*MB);      // 2 MB
    ushort* pw_bf   = (ushort*)((char*)d_ws + 6*MB);      // 2 MB

    cvt_bf16<<<dim3(512), dim3(256), 0, stream>>>(uu, u_bf, 262144);
    cvt_bf16<<<dim3(512), dim3(256), 0, stream>>>(pw, pw_bf, 262144);
    fused_diag<<<dim3(BATCH*64), dim3(256), 0, stream>>>(h, pw_bf, u_bf, lam, pb, partial);
    bcast_out<<<dim3(512), dim3(256), 0, stream>>>(partial, bias, out);
  } else {
    emergency_fused<<<dim3(BATCH*D_), dim3(256), 0, stream>>>(h, lam, uu, bias, pw, pb, out);
  }
}

// Round 12
// 427.986 us; speedup vs baseline: 1.7807x; 1.7403x over previous
//
#include <hip/hip_runtime.h>
#include <hip/hip_bf16.h>

// B=64, D=1024, M=1024, DMODEL=1024, PRED_LEN=96
//   hp[b,i,f] = sum_c h[b,i,c]*pw[f,c] + pb[f]
//   P [b,i,f] = sum_m u[i,m]*lam[b,f,m]
//   diag[b,i] = sum_f hp[b,i,f]*P[b,i,f];  out[b,i,:] = diag[b,i] + bias[i]
//
// R5 skeleton restored (all-bf16 GEMM, proven 293us/937TF/0-conflict):
// cvt2(h,lam f32->bf16, one pass, nt loads) -> ONE fused kernel per
// (b, i-tile, f-tile): hp-tile GEMM -> pack bf16+pb in regs -> P-tile GEMM
// (same counted-vmcnt dbuf core) -> in-register hadamard/rowsum -> 16
// partial strips -> fast 512-block strip-sum broadcast.

#define D_    1024
#define BATCH 64
#define PRED  96

typedef __attribute__((ext_vector_type(8))) short  bf16x8;
typedef __attribute__((ext_vector_type(8))) ushort ushort8;
typedef __attribute__((ext_vector_type(4))) float  f32x4;
typedef __attribute__((ext_vector_type(4))) ushort us4;

__device__ __forceinline__ ushort f2bf(float f){
  union { __hip_bfloat16 b; ushort u; } cv;
  cv.b = __float2bfloat16(f);
  return cv.u;
}
__device__ __forceinline__ float bf2f(ushort v){
  union { ushort u; __hip_bfloat16 b; } cv;
  cv.u = v;
  return __bfloat162float(cv.b);
}

// bijective XCD swizzle (m204 form)
__device__ __forceinline__ int xcd_swz(int orig, int nwg){
  int q = nwg >> 3, r = nwg & 7;
  int x = orig & 7, o = orig >> 3;
  return (x < r ? x*(q+1) : r*(q+1) + (x-r)*q) + o;
}

// async global->LDS, 16B per lane; LDS dest = wave-uniform base + lane*16
__device__ __forceinline__ void gload16(const ushort* g, ushort* l){
  __builtin_amdgcn_global_load_lds(
      (const __attribute__((address_space(1))) void*)g,
      (__attribute__((address_space(3))) void*)l, 16, 0, 0);
}

// ------- tiny f32 -> bf16 convert (u/pw) -------
__global__ __launch_bounds__(256) void cvt_bf16(const float* __restrict__ in,
                                                ushort* __restrict__ out, int n4){
  int stride = (int)gridDim.x * 256;
  for (int i = (int)blockIdx.x*256 + (int)threadIdx.x; i < n4; i += stride){
    f32x4 a = __builtin_nontemporal_load((const f32x4*)in + i);
    us4 o;
    o.x = f2bf(a.x); o.y = f2bf(a.y); o.z = f2bf(a.z); o.w = f2bf(a.w);
    *(us4*)(out + (size_t)i*4) = o;
  }
}

// ------- big f32 -> bf16 convert, h and lam in one pass -------
// nt loads (f32 never re-read); REGULAR stores (bf16 reused by GEMM -> L3).
__global__ __launch_bounds__(256) void cvt2_bf16(
    const float* __restrict__ inA, ushort* __restrict__ outA,
    const float* __restrict__ inB, ushort* __restrict__ outB, int n8each){
  int stride = (int)gridDim.x * 256;
  for (int i = (int)blockIdx.x*256 + (int)threadIdx.x; i < 2*n8each; i += stride){
    const f32x4* src; ushort* dst; int j;
    if (i < n8each){ src = (const f32x4*)inA; dst = outA; j = i; }
    else           { src = (const f32x4*)inB; dst = outB; j = i - n8each; }
    f32x4 a = __builtin_nontemporal_load(src + 2*(size_t)j);
    f32x4 b = __builtin_nontemporal_load(src + 2*(size_t)j + 1);
    ushort8 o;
    o[0]=f2bf(a.x); o[1]=f2bf(a.y); o[2]=f2bf(a.z); o[3]=f2bf(a.w);
    o[4]=f2bf(b.x); o[5]=f2bf(b.y); o[6]=f2bf(b.z); o[7]=f2bf(b.w);
    *(ushort8*)(dst + (size_t)j*8) = o;
  }
}

// Shared K-loop core (depth-2 counted pipeline), proven R3/R5 (0 bank conflicts).
// LDS: sA/sB each 2 x 128x64 ushorts (dbuf).
// T2: LDS[r][chunk] = G[r][chunk ^ (r&7)] via pre-swizzled source; reads XOR back.
#define GEMM_CORE(Apan, Bpan, ACC)                                              \
  {                                                                             \
    _Pragma("unroll")                                                           \
    for (int q = 0; q < 4; ++q){                                                \
      int r0 = q*32 + wv*8;                                                     \
      gload16(Apan + (size_t)(r0 + srow)*D_ + scol, sA + r0*64);                \
      gload16(Bpan + (size_t)(r0 + srow)*D_ + scol, sB + r0*64);                \
    }                                                                           \
    _Pragma("unroll")                                                           \
    for (int q = 0; q < 4; ++q){                                                \
      int r0 = q*32 + wv*8;                                                     \
      gload16(Apan + 64 + (size_t)(r0 + srow)*D_ + scol, sA + 128*64 + r0*64);  \
      gload16(Bpan + 64 + (size_t)(r0 + srow)*D_ + scol, sB + 128*64 + r0*64);  \
    }                                                                           \
    for (int t = 0; t < 16; ++t){                                               \
      const int cur = t & 1;                                                    \
      ushort* sAc = sA + cur*(128*64);                                          \
      ushort* sBc = sB + cur*(128*64);                                          \
      if (t < 15) asm volatile("s_waitcnt vmcnt(8)" ::: "memory");              \
      else        asm volatile("s_waitcnt vmcnt(0)" ::: "memory");              \
      __builtin_amdgcn_s_barrier();                                             \
      bf16x8 af[2][4], bfr[2][4];                                               \
      _Pragma("unroll")                                                         \
      for (int kk = 0; kk < 2; ++kk){                                           \
        int cb = kk*4 + (lane >> 4);                                            \
        _Pragma("unroll")                                                       \
        for (int x = 0; x < 4; ++x){                                            \
          int ra = wr*64 + x*16 + (lane & 15);                                  \
          af[kk][x]  = *(const bf16x8*)(sAc + ra*64 + ((cb ^ (ra & 7)) << 3));  \
          int rb = wc*64 + x*16 + (lane & 15);                                  \
          bfr[kk][x] = *(const bf16x8*)(sBc + rb*64 + ((cb ^ (rb & 7)) << 3));  \
        }                                                                       \
      }                                                                         \
      asm volatile("s_waitcnt lgkmcnt(0)" ::: "memory");                        \
      __builtin_amdgcn_sched_barrier(0);                                        \
      __builtin_amdgcn_s_barrier();                                             \
      if (t < 14){                                                              \
        const ushort* An = Apan + (t+2)*64;                                     \
        const ushort* Bn = Bpan + (t+2)*64;                                     \
        _Pragma("unroll")                                                       \
        for (int q = 0; q < 4; ++q){                                            \
          int r0 = q*32 + wv*8;                                                 \
          gload16(An + (size_t)(r0 + srow)*D_ + scol, sAc + r0*64);             \
          gload16(Bn + (size_t)(r0 + srow)*D_ + scol, sBc + r0*64);             \
        }                                                                       \
      }                                                                         \
      __builtin_amdgcn_s_setprio(1);                                            \
      _Pragma("unroll")                                                         \
      for (int kk = 0; kk < 2; ++kk)                                            \
        _Pragma("unroll")                                                       \
        for (int x = 0; x < 4; ++x)                                             \
          _Pragma("unroll")                                                     \
          for (int y = 0; y < 4; ++y)                                           \
            ACC[x][y] = __builtin_amdgcn_mfma_f32_16x16x32_bf16(                \
                            af[kk][x], bfr[kk][y], ACC[x][y], 0, 0, 0);         \
      __builtin_amdgcn_s_setprio(0);                                            \
    }                                                                           \
  }

// ---------------- fused: hp-tile GEMM + P-tile GEMM + diag epilogue ----------------
__global__ __launch_bounds__(256, 2) void fused_diag(
    const ushort* __restrict__ hbf, const ushort* __restrict__ pwbf,
    const ushort* __restrict__ ubf, const ushort* __restrict__ lambf,
    const float* __restrict__ pb, float* __restrict__ partial, int b0)
{
  __shared__ ushort sA[2*128*64];
  __shared__ ushort sB[2*128*64];
  int bid = xcd_swz((int)blockIdx.x, (int)gridDim.x);
  int bl = bid >> 6;
  int t_ = bid & 63;
  int it = t_ >> 3, ft = t_ & 7;
  const ushort* ApanH = hbf  + ((size_t)bl << 20) + (size_t)(it*128) * D_;
  const ushort* BpanW = pwbf + (size_t)(ft*128) * D_;
  const ushort* ApanU = ubf  + (size_t)(it*128) * D_;
  const ushort* BpanL = lambf + ((size_t)bl << 20) + (size_t)(ft*128) * D_;
  int tid = threadIdx.x, lane = tid & 63, wv = tid >> 6;
  int wr = wv >> 1, wc = wv & 1;
  int srow = lane >> 3;
  int scol = (((lane & 7) ^ srow) << 3);     // T2 pre-swizzled source chunk

  f32x4 acc[4][4];
  #pragma unroll
  for (int x = 0; x < 4; ++x)
    #pragma unroll
    for (int y = 0; y < 4; ++y) acc[x][y] = (f32x4){0.f,0.f,0.f,0.f};

  // ---- loop 1: hp-tile = h @ pw^T ----
  GEMM_CORE(ApanH, BpanW, acc)

  // pack hp (+pb) to bf16 in registers; reset acc for loop 2
  us4 hp_pk[4][4];
  #pragma unroll
  for (int y = 0; y < 4; ++y){
    int gk = ft*128 + wc*64 + y*16 + (lane & 15);
    float pbv = pb[gk];
    #pragma unroll
    for (int x = 0; x < 4; ++x){
      us4 p;
      p.x = f2bf(acc[x][y][0] + pbv); p.y = f2bf(acc[x][y][1] + pbv);
      p.z = f2bf(acc[x][y][2] + pbv); p.w = f2bf(acc[x][y][3] + pbv);
      hp_pk[x][y] = p;
      acc[x][y] = (f32x4){0.f,0.f,0.f,0.f};
    }
  }

  // ---- loop 2: P-tile = u @ lam^T ----
  GEMM_CORE(ApanU, BpanL, acc)

  // ---- epilogue: ps = rowsum over this wave's 64 cols of hp .* P ----
  f32x4 ps[4];
  #pragma unroll
  for (int x = 0; x < 4; ++x) ps[x] = (f32x4){0.f,0.f,0.f,0.f};
  #pragma unroll
  for (int y = 0; y < 4; ++y)
    #pragma unroll
    for (int x = 0; x < 4; ++x){
      ps[x][0] += bf2f(hp_pk[x][y].x) * acc[x][y][0];
      ps[x][1] += bf2f(hp_pk[x][y].y) * acc[x][y][1];
      ps[x][2] += bf2f(hp_pk[x][y].z) * acc[x][y][2];
      ps[x][3] += bf2f(hp_pk[x][y].w) * acc[x][y][3];
    }
  // butterfly over the 16 cols (lane bits 0..3); preserves row group (lane>>4)
  #pragma unroll
  for (int x = 0; x < 4; ++x)
    #pragma unroll
    for (int r = 0; r < 4; ++r){
      float v = ps[x][r];
      #pragma unroll
      for (int mm = 1; mm < 16; mm <<= 1) v += __shfl_xor(v, mm, 64);
      ps[x][r] = v;
    }
  // deterministic partial strips: strip = ft*2 + wc  (16 strips)
  if ((lane & 15) == 0){
    int strip = ft*2 + wc;
    float* pdst = partial + (size_t)strip*(BATCH*D_) + (size_t)(b0 + bl)*D_;
    #pragma unroll
    for (int x = 0; x < 4; ++x){
      int gi0 = it*128 + wr*64 + x*16 + (lane >> 4)*4;
      #pragma unroll
      for (int r = 0; r < 4; ++r) pdst[gi0 + r] = ps[x][r];
    }
  }
}

// ------- K3: diag = sum(strips) + bias; broadcast to 96 (fast 512-block) -------
__global__ __launch_bounds__(256) void bcast_out(
    const float* __restrict__ partial, const float* __restrict__ bias,
    float* __restrict__ out)
{
  int tid = threadIdx.x;
  int row = (int)blockIdx.x*128 + (tid >> 1);   // 512 blocks x 128 rows
  int half = tid & 1;
  int i = row & (D_-1);
  float s = bias[i];
  #pragma unroll
  for (int st = 0; st < 16; ++st) s += partial[(size_t)st*(BATCH*D_) + row];
  f32x4 v = {s, s, s, s};
  float* dst = out + (size_t)row*PRED + half*48;
  #pragma unroll
  for (int j = 0; j < 12; ++j) ((f32x4*)dst)[j] = v;
}

// ---------------- emergency path: no workspace needed (slow, correct) ----------------
__global__ __launch_bounds__(256) void emergency_fused(
    const float* __restrict__ h, const float* __restrict__ lam,
    const float* __restrict__ uu, const float* __restrict__ bias,
    const float* __restrict__ pw, const float* __restrict__ pb,
    float* __restrict__ out)
{
  int b = blockIdx.x >> 10;
  int i = blockIdx.x & (D_-1);
  __shared__ float hps[D_];
  __shared__ float red[4];
  __shared__ float dv;
  const float* hrow = h + ((size_t)b << 20) + (size_t)i*D_;
  for (int f = threadIdx.x; f < D_; f += 256){
    const float* pwr = pw + (size_t)f*D_;
    float s = pb[f];
    for (int c = 0; c < D_; ++c) s += hrow[c]*pwr[c];
    hps[f] = s;
  }
  __syncthreads();
  const float* urow = uu + (size_t)i*D_;
  float d = 0.f;
  for (int f = threadIdx.x; f < D_; f += 256){
    const float* lr = lam + ((size_t)b << 20) + (size_t)f*D_;
    float p = 0.f;
    for (int m = 0; m < D_; ++m) p += lr[m]*urow[m];
    d += hps[f]*p;
  }
  for (int off = 32; off; off >>= 1) d += __shfl_down(d, off, 64);
  if ((threadIdx.x & 63) == 0) red[threadIdx.x >> 6] = d;
  __syncthreads();
  if (threadIdx.x == 0) dv = red[0]+red[1]+red[2]+red[3] + bias[i];
  __syncthreads();
  if (threadIdx.x < PRED) out[(size_t)blockIdx.x*PRED + threadIdx.x] = dv;
}

extern "C" void kernel_launch(void* const* d_in, const int* in_sizes, int n_in,
                              void* d_out, int out_size, void* d_ws, size_t ws_size,
                              hipStream_t stream) {
  const float* h    = (const float*)d_in[0];
  const float* lam  = (const float*)d_in[1];
  const float* uu   = (const float*)d_in[2];
  const float* bias = (const float*)d_in[3];
  const float* pw   = (const float*)d_in[4];
  const float* pb   = (const float*)d_in[5];
  float* out = (float*)d_out;

  const size_t MB = 1ull << 20;
  const size_t FIXED = 4*MB /*partial*/ + 2*MB /*u_bf*/ + 2*MB /*pw_bf*/;

  if (ws_size >= FIXED + 4*MB) {
    float*  partial = (float*)d_ws;
    ushort* u_bf    = (ushort*)((char*)d_ws + 4*MB);
    ushort* pw_bf   = (ushort*)((char*)d_ws + 6*MB);
    char*   cbase   = (char*)d_ws + 8*MB;
    int cnb = (int)((ws_size - FIXED) / (4*MB));   // per-b: h_bf 2MB + lam_bf 2MB
    if (cnb > BATCH) cnb = BATCH;

    cvt_bf16<<<dim3(512), dim3(256), 0, stream>>>(uu, u_bf, 262144);
    cvt_bf16<<<dim3(512), dim3(256), 0, stream>>>(pw, pw_bf, 262144);

    for (int b0 = 0; b0 < BATCH; b0 += cnb){
      int nb = (BATCH - b0) < cnb ? (BATCH - b0) : cnb;
      ushort* h_bf   = (ushort*)cbase;
      ushort* lam_bf = (ushort*)(cbase + (size_t)nb*2*MB);
      cvt2_bf16<<<dim3(2048), dim3(256), 0, stream>>>(
          h   + ((size_t)b0 << 20), h_bf,
          lam + ((size_t)b0 << 20), lam_bf, nb*131072);
      fused_diag<<<dim3(nb*64), dim3(256), 0, stream>>>(h_bf, pw_bf, u_bf, lam_bf, pb, partial, b0);
    }
    bcast_out<<<dim3(512), dim3(256), 0, stream>>>(partial, bias, out);
  } else {
    emergency_fused<<<dim3(BATCH*D_), dim3(256), 0, stream>>>(h, lam, uu, bias, pw, pb, out);
  }
}